// Round 1
// baseline (9489.536 us; speedup 1.0000x reference)
//
#include <hip/hip_runtime.h>
#include <hip/hip_bf16.h>

#define VV 50000
#define DD 256
#define HH 128
#define G4 512
#define BB 8
#define SS 512
#define TT 100
#define T1 101
#define GAMMA 1.0f
#define LOG2E 1.44269504f

__device__ inline float rcpf_(float x){
#if __has_builtin(__builtin_amdgcn_rcpf)
  return __builtin_amdgcn_rcpf(x);
#else
  return 1.0f/x;
#endif
}
__device__ inline float exp2f_(float x){
#if __has_builtin(__builtin_amdgcn_exp2f)
  return __builtin_amdgcn_exp2f(x);
#else
  return exp2f(x);
#endif
}
__device__ inline float log2f_(float x){
#if __has_builtin(__builtin_amdgcn_logf)
  return __builtin_amdgcn_logf(x);
#else
  return log2f(x);
#endif
}
__device__ inline float fexp(float x){ return exp2f_(x*LOG2E); }
__device__ inline float sigf(float x){ return rcpf_(1.f + fexp(-x)); }
__device__ inline float tanh_(float x){
  x = fminf(12.f, fmaxf(-12.f, x));
  float e = fexp(2.f*x);
  return (e-1.f)*rcpf_(e+1.f);
}
__device__ inline unsigned short f2bf(float x){
  unsigned u = __float_as_uint(x);
  return (unsigned short)((u + 0x7fffu + ((u>>16)&1u)) >> 16);
}
__device__ inline unsigned pack2(float a, float b){ return (unsigned)f2bf(a) | ((unsigned)f2bf(b)<<16); }
__device__ inline float blo(unsigned u){ return __uint_as_float(u<<16); }
__device__ inline float bhi(unsigned u){ return __uint_as_float(u & 0xffff0000u); }
__device__ inline float bf2f(unsigned short s){ return __uint_as_float(((unsigned)s)<<16); }

// ---------------- prep: small weight transposes/packs ----------------
__global__ void __launch_bounds__(256) k_prep_small(
    const float* Wih_f, const float* Wih_b, const float* Whh_f, const float* Whh_b,
    const float* W1,
    float* WihT_f, float* WihT_b, uint2* WT4_f, uint2* WT4_b,
    float* W1hT, float* W1aT){
  int i = blockIdx.x*256 + threadIdx.x;
  if (i < 131072){ int k = i>>9, j = i&511; WihT_f[i] = Wih_f[j*DD + k]; return; }
  i -= 131072;
  if (i < 131072){ int k = i>>9, j = i&511; WihT_b[i] = Wih_b[j*DD + k]; return; }
  i -= 131072;
  if (i < 16384){ int k4 = i>>9, j = i&511; const float* p = Whh_f + j*HH + 4*k4;
    WT4_f[i] = make_uint2(pack2(p[0],p[1]), pack2(p[2],p[3])); return; }
  i -= 16384;
  if (i < 16384){ int k4 = i>>9, j = i&511; const float* p = Whh_b + j*HH + 4*k4;
    WT4_b[i] = make_uint2(pack2(p[0],p[1]), pack2(p[2],p[3])); return; }
  i -= 16384;
  if (i < 16384){ int j = i>>7, k = i&127; W1hT[i] = W1[k*385 + 256 + j]; return; }
  i -= 16384;
  if (i < 32768){ int d = i>>7, k = i&127; W1aT[i] = W1[k*385 + d]; return; }
}

// ---------------- prep: Wl -> bf16x2 transposed [k2][v] ----------------
__global__ void __launch_bounds__(256) k_prep_wl(const float* Wl, unsigned* WlT2){
  __shared__ unsigned tile[64*192];
  int tid = threadIdx.x;
  int v0 = blockIdx.x*64;
  for (int it=0; it<48; ++it){
    int f = it*256 + tid;            // f < 12288 = 64*192
    int vs = f/192, k2 = f - vs*192;
    int v = v0 + vs;
    if (v < VV){
      float2 w = ((const float2*)(Wl + (size_t)v*384))[k2];
      tile[vs*192 + k2] = pack2(w.x, w.y);
    }
  }
  __syncthreads();
  for (int it=0; it<48; ++it){
    int f = it*256 + tid;
    int k2 = f>>6, vs = f&63;
    int v = v0 + vs;
    if (v < VV) WlT2[(size_t)k2*VV + v] = tile[vs*192 + k2];
  }
}

// ---------------- embedding gather + ridx ----------------
__global__ void k_embed(const int* text, const int* tlen, const float* wv,
                        float* emb, int* ridx){
  int blk = blockIdx.x;            // b*512+s
  int b = blk>>9, s = blk&511;
  int tok = text[blk];
  const float4* src = (const float4*)(wv + (size_t)tok*DD);
  float4* dst = (float4*)(emb + (size_t)blk*DD);
  dst[threadIdx.x] = src[threadIdx.x];
  if (threadIdx.x==0){ int len = tlen[b]; ridx[blk] = (s < len) ? (len-1-s) : s; }
}

// ---------------- X = emb @ Wih^T + bih + bhh  (optionally reversed gather) ----
__global__ void __launch_bounds__(256) k_xgemm(const float* emb, const int* ridx,
    const float* WihT, const float* bi, const float* bh, float* X, int rev){
  __shared__ float e_l[8][256];
  int tid = threadIdx.x;
  int g0 = blockIdx.x*8;
  int b = g0>>9;
  for (int r=0;r<8;r++){
    int s = (g0+r)&511;
    int src = rev ? ridx[b*SS + s] : s;
    e_l[r][tid] = emb[((size_t)(b*SS+src))*DD + tid];
  }
  __syncthreads();
  int j0 = tid, j1 = tid+256;
  float acc0[8], acc1[8];
  #pragma unroll
  for (int r=0;r<8;r++){ acc0[r]=0.f; acc1[r]=0.f; }
  for (int k=0;k<256;k++){
    float w0 = WihT[k*G4 + j0];
    float w1 = WihT[k*G4 + j1];
    #pragma unroll
    for (int r=0;r<8;r++){ float e = e_l[r][k]; acc0[r] += e*w0; acc1[r] += e*w1; }
  }
  float bb0 = bi[j0]+bh[j0], bb1 = bi[j1]+bh[j1];
  for (int r=0;r<8;r++){
    X[((size_t)(g0+r))*G4 + j0] = acc0[r] + bb0;
    X[((size_t)(g0+r))*G4 + j1] = acc1[r] + bb1;
  }
}

// ---------------- encoder recurrence: one block per (b, dir) ----------------
__global__ void __launch_bounds__(512) k_encoder(const float* Xf, const float* Xb,
    const uint2* WT4f, const uint2* WT4b, const int* tlen,
    float* out_f, float* out_r, float* h0, float* c0){
  __shared__ __align__(16) float h_l[128];
  __shared__ float c_l[128];
  __shared__ float g_l[512];
  int tid = threadIdx.x;
  int b = blockIdx.x, dir = blockIdx.y;
  const float* X = dir ? Xb : Xf;
  const uint2* WT = dir ? WT4b : WT4f;
  float* out = dir ? out_r : out_f;
  if (tid < 128){ h_l[tid]=0.f; c_l[tid]=0.f; }
  __syncthreads();
  int len = tlen[b];
  const float4* h4 = (const float4*)h_l;
  for (int t=0;t<len;t++){
    float acc = X[((size_t)(b*SS+t))*G4 + tid];
    #pragma unroll 8
    for (int k4=0;k4<32;k4++){
      uint2 w = WT[k4*G4 + tid];
      float4 hv = h4[k4];
      acc += blo(w.x)*hv.x + bhi(w.x)*hv.y + blo(w.y)*hv.z + bhi(w.y)*hv.w;
    }
    g_l[tid] = acc;
    __syncthreads();
    if (tid < 128){
      float ii = sigf(g_l[tid]);
      float ff = sigf(g_l[128+tid]);
      float gg = tanh_(g_l[256+tid]);
      float oo = sigf(g_l[384+tid]);
      float cv = ff*c_l[tid] + ii*gg;
      float hn = oo*tanh_(cv);
      c_l[tid]=cv; h_l[tid]=hn;
      out[((size_t)(b*SS+t))*HH + tid] = hn;
    }
    __syncthreads();
  }
  for (int f = tid; f < (SS-len)*HH; f += 512){
    int s = len + (f>>7), j = f&127;
    out[((size_t)(b*SS+s))*HH + j] = 0.f;
  }
  if (dir==0 && tid<128){ h0[b*HH+tid]=h_l[tid]; c0[b*HH+tid]=c_l[tid]; }
}

// ---------------- post-encoder: ts_bf16 + TS1T = ts @ W1[:, :256]^T (transposed) --
__global__ void __launch_bounds__(256) k_post(const float* out_f, const float* out_r,
    const int* ridx, const float* W1aT, unsigned short* ts_bf, float* TS1T){
  __shared__ float ts_l[32*256];
  int tid = threadIdx.x;
  int b = blockIdx.x, chunk = blockIdx.y;
  int s0 = chunk*32;
  for (int it=0; it<32; ++it){
    int s = s0 + it;
    int d = tid;
    float v;
    if (d < 128) v = out_f[((size_t)(b*SS+s))*HH + d];
    else        v = out_r[((size_t)(b*SS + ridx[b*SS+s]))*HH + (d-128)];
    ts_l[it*256 + d] = v;
    ts_bf[((size_t)(b*SS+s))*256 + d] = f2bf(v);
  }
  __syncthreads();
  int k = tid & 127, half = tid >> 7;
  float acc[16];
  #pragma unroll
  for (int i=0;i<16;i++) acc[i]=0.f;
  for (int d=0;d<256;d++){
    float w = W1aT[d*128 + k];
    #pragma unroll
    for (int i=0;i<16;i++) acc[i] += ts_l[(half*16+i)*256 + d]*w;
  }
  for (int i=0;i<16;i++){
    int s = s0 + half*16 + i;
    TS1T[((size_t)(b*128+k))*SS + s] = acc[i];
  }
}

// ---------------- decoder state init ----------------
__global__ void k_init(const float* h0, const float* c0, float* h, float* c,
                       float* cov, float* loss){
  int b = blockIdx.x, tid = threadIdx.x;
  if (tid<128){ h[b*HH+tid]=h0[b*HH+tid]; c[b*HH+tid]=c0[b*HH+tid]; }
  cov[b*SS + tid] = 0.f; cov[b*SS + 256 + tid] = 0.f;
  if (b==0 && tid==0) loss[0]=0.f;
}

// ---------------- decoder gate GEMV slice (all blocks) ----------------
struct CArgs {
  const int* summary; const float* wv; const float* Wdih; const float* Wdhh;
  const float* bdih; const float* bdhh; const float* h; const float* hn;
  const float* context; const float* Wl; const unsigned* WlT2; const float* bl;
  float* gates; float* pm; float* ps; float* tgt; int useWl; int t;
};

__device__ inline void dec_gates(int tstep, const CArgs& a){
  int tid = threadIdx.x;
  int e_sub = tid >> 4, l16 = tid & 15;
  int e = blockIdx.x*16 + e_sub;
  int b = e >> 9, j = e & 511;
  int tok = a.summary[b*T1 + tstep];
  const float* xr = a.wv + (size_t)tok*DD;
  const float* wr = a.Wdih + (size_t)j*DD;
  float acc = 0.f;
  #pragma unroll
  for (int i=0;i<16;i++){ int k = l16 + 16*i; acc += xr[k]*wr[k]; }
  const float* hr = a.h + b*HH;
  const float* wh = a.Wdhh + (size_t)j*HH;
  #pragma unroll
  for (int i=0;i<8;i++){ int k = l16 + 16*i; acc += hr[k]*wh[k]; }
  #pragma unroll
  for (int off=8; off>=1; off>>=1) acc += __shfl_xor(acc, off, 64);
  if (l16==0) a.gates[b*G4 + j] = acc + a.bdih[j] + a.bdhh[j];
}

__global__ void __launch_bounds__(256) k_stepC(CArgs a){
  __shared__ float xs_l[BB*384];
  __shared__ float red_l[64];
  int tid = threadIdx.x;
  int t = a.t;
  if (t >= 0){
    for (int f = tid; f < BB*384; f += 256){
      int b = f/384, k = f - b*384;
      xs_l[f] = (k < 256) ? a.context[b*256+k] : a.hn[b*HH + (k-256)];
    }
    __syncthreads();
    int v = blockIdx.x*196 + tid;
    float acc[BB];
    bool act = (tid < 196) && (v < VV);
    if (act){
      #pragma unroll
      for (int b=0;b<BB;b++) acc[b] = a.bl[v];
      if (a.useWl){
        const unsigned* wp = a.WlT2 + v;
        for (int k2=0;k2<192;k2++){
          unsigned u = wp[(size_t)k2*VV];
          float f0 = blo(u), f1 = bhi(u);
          const float* x = xs_l + 2*k2;
          #pragma unroll
          for (int b=0;b<BB;b++){ acc[b] += f0*x[b*384] + f1*x[b*384+1]; }
        }
      } else {
        const float* wr = a.Wl + (size_t)v*384;
        for (int k=0;k<384;k++){
          float w = wr[k];
          #pragma unroll
          for (int b=0;b<BB;b++) acc[b] += w*xs_l[b*384+k];
        }
      }
      #pragma unroll
      for (int b=0;b<BB;b++) if (v == a.summary[b*T1 + t+1]) a.tgt[b] = acc[b];
    } else {
      #pragma unroll
      for (int b=0;b<BB;b++) acc[b] = -1e30f;
    }
    int wid = tid >> 6, lane = tid & 63;
    float mb[BB];
    #pragma unroll
    for (int b=0;b<BB;b++){
      float m = acc[b];
      #pragma unroll
      for (int off=32;off>=1;off>>=1) m = fmaxf(m, __shfl_xor(m, off, 64));
      if (lane==0) red_l[b*4+wid] = m;
    }
    __syncthreads();
    #pragma unroll
    for (int b=0;b<BB;b++)
      mb[b] = fmaxf(fmaxf(red_l[b*4],red_l[b*4+1]),fmaxf(red_l[b*4+2],red_l[b*4+3]));
    __syncthreads();
    #pragma unroll
    for (int b=0;b<BB;b++){
      float e = act ? fexp(acc[b]-mb[b]) : 0.f;
      #pragma unroll
      for (int off=32;off>=1;off>>=1) e += __shfl_xor(e, off, 64);
      if (lane==0) red_l[b*4+wid] = e;
    }
    __syncthreads();
    if (tid < BB){
      int b = tid;
      a.pm[blockIdx.x*BB + b] = mb[b];
      a.ps[blockIdx.x*BB + b] = red_l[b*4]+red_l[b*4+1]+red_l[b*4+2]+red_l[b*4+3];
    }
  }
  if (t+1 < TT) dec_gates(t+1, a);
}

// ---------------- combine: LSE + loss accumulate ----------------
__device__ void dec_combine(int tc, const float* pm, const float* ps, const float* tgt,
                            const float* covloss, const int* slen, float* loss, float* red){
  int tid = threadIdx.x;
  int b = tid >> 5, i = tid & 31;
  float m = -1e30f;
  for (int jb=i; jb<256; jb+=32) m = fmaxf(m, pm[jb*BB + b]);
  #pragma unroll
  for (int off=16;off>=1;off>>=1) m = fmaxf(m, __shfl_xor(m, off, 64));
  float s = 0.f;
  for (int jb=i; jb<256; jb+=32) s += ps[jb*BB + b]*fexp(pm[jb*BB+b]-m);
  #pragma unroll
  for (int off=16;off>=1;off>>=1) s += __shfl_xor(s, off, 64);
  if (i==0){
    float lse = m + log2f_(s)*0.6931472f;
    float nll = lse - tgt[b];
    bool val = slen[b] > tc+1;
    red[b] = val ? (nll + GAMMA*covloss[b]) : 0.f;
  }
  __syncthreads();
  if (tid==0){
    float sum=0.f;
    #pragma unroll
    for (int b2=0;b2<BB;b2++) sum += red[b2];
    loss[0] += sum;
  }
}

// ---------------- decoder cell + attention (blocks 0-7) + combine (block 8) ----
struct ABArgs {
  const int* tlen; const int* slen; const float* gates;
  float* h; float* c; float* hn;
  const float* W1hT; const float* b1; const float* W2; const float* W1;
  const float* TS1T; const unsigned short* ts_bf;
  float* cov; float* context; float* covloss;
  const float* pm; const float* ps; const float* tgt; float* loss; int t;
};

__global__ void __launch_bounds__(256) k_stepAB(ABArgs a){
  __shared__ float uh_l[128];
  __shared__ float hnl[128];
  __shared__ float red_l[256];
  __shared__ float attn_l[512];
  __shared__ float cred[8];
  int tid = threadIdx.x;
  int t = a.t;
  if (blockIdx.x == 8){
    if (t > 0)
      dec_combine(t-1, a.pm, a.ps, a.tgt, a.covloss + (((t-1)&1)*BB), a.slen, a.loss, cred);
    return;
  }
  int b = blockIdx.x;
  bool val = a.slen[b] > t+1;
  // ---- stage A: LSTM cell ----
  if (tid < 128){
    int j = tid;
    float gi = a.gates[b*G4 + j];
    float gf = a.gates[b*G4 + 128 + j];
    float gg = a.gates[b*G4 + 256 + j];
    float go = a.gates[b*G4 + 384 + j];
    float ii = sigf(gi), ff = sigf(gf), g2 = tanh_(gg), oo = sigf(go);
    float cn = ff*a.c[b*HH+j] + ii*g2;
    float hv = oo*tanh_(cn);
    hnl[j] = hv;
    a.hn[b*HH+j] = hv;
    if (val){ a.h[b*HH+j] = hv; a.c[b*HH+j] = cn; }
  }
  __syncthreads();
  if (tid < 128){
    float acc = 0.f;
    for (int j=0;j<128;j++) acc += hnl[j]*a.W1hT[j*128 + tid];
    uh_l[tid] = acc + a.b1[tid];
  }
  __syncthreads();
  // ---- stage B: attention scores ----
  float cv0 = a.cov[b*SS + tid], cv1 = a.cov[b*SS + 256 + tid];
  float sc0 = 0.f, sc1 = 0.f;
  const float* tsp = a.TS1T + (size_t)b*128*SS;
  for (int k=0;k<128;k++){
    float ub = uh_l[k];
    float wc = a.W1[k*385 + 384];
    float w2 = a.W2[k];
    float p0 = tsp[k*SS + tid]       + ub + cv0*wc;
    float p1 = tsp[k*SS + 256 + tid] + ub + cv1*wc;
    sc0 += tanh_(p0)*w2;
    sc1 += tanh_(p1)*w2;
  }
  red_l[tid] = fmaxf(sc0, sc1);
  __syncthreads();
  for (int off=128; off>=1; off>>=1){
    if (tid<off) red_l[tid] = fmaxf(red_l[tid], red_l[tid+off]);
    __syncthreads();
  }
  float m = red_l[0];
  __syncthreads();
  float e0 = fexp(sc0 - m), e1 = fexp(sc1 - m);
  red_l[tid] = e0 + e1;
  __syncthreads();
  for (int off=128; off>=1; off>>=1){
    if (tid<off) red_l[tid] += red_l[tid+off];
    __syncthreads();
  }
  float rl = rcpf_(red_l[0]);
  __syncthreads();
  float a0 = e0*rl, a1 = e1*rl;
  attn_l[tid] = a0; attn_l[256+tid] = a1;
  red_l[tid] = fminf(cv0,a0) + fminf(cv1,a1);
  __syncthreads();
  for (int off=128; off>=1; off>>=1){
    if (tid<off) red_l[tid] += red_l[tid+off];
    __syncthreads();
  }
  if (tid==0) a.covloss[(t&1)*BB + b] = red_l[0];
  if (val){ a.cov[b*SS+tid] = cv0 + a0; a.cov[b*SS+256+tid] = cv1 + a1; }
  __syncthreads();
  // ---- context ----
  int len = a.tlen[b];
  float accd = 0.f;
  const unsigned short* tb = a.ts_bf + (size_t)b*SS*256 + tid;
  for (int s=0;s<len;s++) accd += attn_l[s]*bf2f(tb[(size_t)s*256]);
  a.context[b*256 + tid] = accd;
}

__global__ void k_fin(const float* pm, const float* ps, const float* tgt,
                      const float* covloss, const int* slen, float* loss, float* out){
  __shared__ float cred[8];
  dec_combine(TT-1, pm, ps, tgt, covloss + (((TT-1)&1)*BB), slen, loss, cred);
  if (threadIdx.x==0) out[0] = loss[0] * (1.0f/TT);
}

// ---------------- host ----------------
extern "C" void kernel_launch(void* const* d_in, const int* in_sizes, int n_in,
                              void* d_out, int out_size, void* d_ws, size_t ws_size,
                              hipStream_t stream){
  const int* text      = (const int*)d_in[0];
  const int* tlen      = (const int*)d_in[1];
  const int* summary   = (const int*)d_in[2];
  const int* slen      = (const int*)d_in[3];
  const float* wv      = (const float*)d_in[4];
  const float* Wih_f   = (const float*)d_in[5];
  const float* Whh_f   = (const float*)d_in[6];
  const float* bih_f   = (const float*)d_in[7];
  const float* bhh_f   = (const float*)d_in[8];
  const float* Wih_b   = (const float*)d_in[9];
  const float* Whh_b   = (const float*)d_in[10];
  const float* bih_b   = (const float*)d_in[11];
  const float* bhh_b   = (const float*)d_in[12];
  const float* Wdih    = (const float*)d_in[13];
  const float* Wdhh    = (const float*)d_in[14];
  const float* bdih    = (const float*)d_in[15];
  const float* bdhh    = (const float*)d_in[16];
  const float* W1      = (const float*)d_in[17];
  const float* b1      = (const float*)d_in[18];
  const float* W2      = (const float*)d_in[19];
  const float* Wl      = (const float*)d_in[21];
  const float* bl      = (const float*)d_in[22];

  char* ws = (char*)d_ws;
  size_t off = 0;
  auto alloc = [&](size_t n)->void*{
    off = (off + 255) & ~(size_t)255;
    void* p = ws + off; off += n; return p;
  };

  float* emb     = (float*)alloc((size_t)BB*SS*DD*4);
  int*   ridx    = (int*)  alloc((size_t)BB*SS*4);
  float* WihT_f  = (float*)alloc((size_t)256*512*4);
  float* WihT_b  = (float*)alloc((size_t)256*512*4);
  uint2* WT4_f   = (uint2*)alloc((size_t)32*512*8);
  uint2* WT4_b   = (uint2*)alloc((size_t)32*512*8);
  float* W1hT    = (float*)alloc((size_t)128*128*4);
  float* W1aT    = (float*)alloc((size_t)256*128*4);
  float* Xf      = (float*)alloc((size_t)BB*SS*G4*4);
  float* Xb      = (float*)alloc((size_t)BB*SS*G4*4);
  float* out_f   = (float*)alloc((size_t)BB*SS*HH*4);
  float* out_r   = (float*)alloc((size_t)BB*SS*HH*4);
  unsigned short* ts_bf = (unsigned short*)alloc((size_t)BB*SS*256*2);
  float* TS1T    = (float*)alloc((size_t)BB*128*SS*4);
  float* h0      = (float*)alloc(BB*HH*4);
  float* c0      = (float*)alloc(BB*HH*4);
  float* h       = (float*)alloc(BB*HH*4);
  float* c       = (float*)alloc(BB*HH*4);
  float* hn      = (float*)alloc(BB*HH*4);
  float* cov     = (float*)alloc((size_t)BB*SS*4);
  float* gates   = (float*)alloc((size_t)BB*G4*4);
  float* context = (float*)alloc((size_t)BB*256*4);
  float* covloss = (float*)alloc(2*BB*4);
  float* tgt     = (float*)alloc(BB*4);
  float* pm      = (float*)alloc((size_t)256*BB*4);
  float* ps      = (float*)alloc((size_t)256*BB*4);
  float* loss    = (float*)alloc(4);
  off = (off + 255) & ~(size_t)255;
  size_t wl_bytes = (size_t)192*VV*4;
  int useWl = (off + wl_bytes <= ws_size) ? 1 : 0;
  unsigned* WlT2 = (unsigned*)(ws + off);

  k_prep_small<<<1344,256,0,stream>>>(Wih_f,Wih_b,Whh_f,Whh_b,W1,
                                      WihT_f,WihT_b,WT4_f,WT4_b,W1hT,W1aT);
  if (useWl) k_prep_wl<<<782,256,0,stream>>>(Wl, WlT2);
  k_embed<<<BB*SS,64,0,stream>>>(text, tlen, wv, emb, ridx);
  k_xgemm<<<512,256,0,stream>>>(emb, ridx, WihT_f, bih_f, bhh_f, Xf, 0);
  k_xgemm<<<512,256,0,stream>>>(emb, ridx, WihT_b, bih_b, bhh_b, Xb, 1);
  k_encoder<<<dim3(8,2),512,0,stream>>>(Xf,Xb,WT4_f,WT4_b,tlen,out_f,out_r,h0,c0);
  k_post<<<dim3(8,16),256,0,stream>>>(out_f,out_r,ridx,W1aT,ts_bf,TS1T);
  k_init<<<8,256,0,stream>>>(h0,c0,h,c,cov,loss);

  CArgs ca;
  ca.summary=summary; ca.wv=wv; ca.Wdih=Wdih; ca.Wdhh=Wdhh; ca.bdih=bdih; ca.bdhh=bdhh;
  ca.h=h; ca.hn=hn; ca.context=context; ca.Wl=Wl; ca.WlT2=WlT2; ca.bl=bl;
  ca.gates=gates; ca.pm=pm; ca.ps=ps; ca.tgt=tgt; ca.useWl=useWl; ca.t=-1;
  k_stepC<<<256,256,0,stream>>>(ca);

  for (int t=0;t<TT;t++){
    ABArgs aa;
    aa.tlen=tlen; aa.slen=slen; aa.gates=gates; aa.h=h; aa.c=c; aa.hn=hn;
    aa.W1hT=W1hT; aa.b1=b1; aa.W2=W2; aa.W1=W1; aa.TS1T=TS1T; aa.ts_bf=ts_bf;
    aa.cov=cov; aa.context=context; aa.covloss=covloss;
    aa.pm=pm; aa.ps=ps; aa.tgt=tgt; aa.loss=loss; aa.t=t;
    k_stepAB<<<9,256,0,stream>>>(aa);
    ca.t = t;
    k_stepC<<<256,256,0,stream>>>(ca);
  }
  k_fin<<<1,256,0,stream>>>(pm, ps, tgt, covloss, slen, loss, (float*)d_out);
}